// Round 13
// baseline (112.123 us; speedup 1.0000x reference)
//
#include <hip/hip_runtime.h>

typedef __bf16 bf16;
typedef _Float16 f16;
typedef __attribute__((ext_vector_type(8))) __bf16 bf16x8;
typedef __attribute__((ext_vector_type(4))) __bf16 bf16x4;
typedef __attribute__((ext_vector_type(8))) _Float16 f16x8;
typedef __attribute__((ext_vector_type(4))) _Float16 f16x4;
typedef __attribute__((ext_vector_type(4))) float f32x4;

constexpr int Bn = 16, Ln = 1024, Dn = 256;

__device__ __forceinline__ float maskf(float m) { return m + (1.0f - m) * 1e30f; }

__device__ __forceinline__ void gload16(const void* g, void* l) {
  __builtin_amdgcn_global_load_lds((const __attribute__((address_space(1))) void*)g,
                                   (__attribute__((address_space(3))) void*)l, 16, 0, 0);
}

// counted-waitcnt pipeline primitives (T4). BARR = compiler-fenced hw barrier.
#define VMCNT(N) asm volatile("s_waitcnt vmcnt(" #N ")" ::: "memory")
#define LGKM0 asm volatile("s_waitcnt lgkmcnt(0)" ::: "memory")
#define BARR                                  \
  do {                                        \
    asm volatile("" ::: "memory");            \
    __builtin_amdgcn_s_barrier();             \
    asm volatile("" ::: "memory");            \
  } while (0)

// ---- 512-thread staging: 128 rows x 64 k tile; pre-swizzle GLOBAL source
// (slot ^= row&7) so LDS dst stays linear (rule #21); read-side XOR restores
// conflict-free banking. ----
__device__ __forceinline__ void stage512(const bf16* __restrict__ G, int ldg, int k0,
                                         bf16* L, int tid, int wid) {
#pragma unroll
  for (int p = 0; p < 2; ++p) {                     // 128 rows x 64 k
    int u = tid + (p << 9);
    int row = u >> 3, s = u & 7;
    int kk = ((s ^ (row & 7)) << 3);
    gload16(G + (size_t)row * ldg + k0 + kk, L + ((p << 9) + (wid << 6)) * 8);
  }
}

// swizzled read address within a 64-col (128B-row) LDS tile
__device__ __forceinline__ const bf16* swzp(const bf16* L, int row, int slot) {
  return L + row * 64 + ((slot ^ (row & 7)) << 3);
}

// ---------------- fused prep: dots s0,s1; cm=bf16(c*cqw); qb=bf16(q);
// cT,qT transposed bf16. (chunk0 copy of c lives in g_cq's epilogue.) -------
__global__ __launch_bounds__(256) void k_prep2(
    const float* __restrict__ c, const float* __restrict__ q,
    const float* __restrict__ cw, const float* __restrict__ qw,
    const float* __restrict__ cqw, bf16* __restrict__ cm, bf16* __restrict__ qb,
    bf16* __restrict__ cT, bf16* __restrict__ qT,
    float* __restrict__ s0, float* __restrict__ s1) {
  __shared__ __align__(16) bf16 tc[32][264];
  __shared__ __align__(16) bf16 tq[32][264];
  int blk = blockIdx.x;          // 512 blocks
  int b = blk >> 5;
  int l0 = (blk & 31) << 5;
  int t = threadIdx.x;
  int rl = t >> 3;               // local row 0..31
  int c0 = (t & 7) << 5;         // col start (32 cols/thread)
  int grow = b * Ln + l0 + rl;
  size_t base = (size_t)grow * Dn + c0;
  float4 cv[8], qv[8];
#pragma unroll
  for (int k = 0; k < 8; ++k) {
    cv[k] = *(const float4*)&c[base + k * 4];
    qv[k] = *(const float4*)&q[base + k * 4];
  }
  float d0 = 0.f, d1 = 0.f;
#pragma unroll
  for (int k = 0; k < 8; ++k) {
    float4 w = *(const float4*)&cw[c0 + k * 4];
    float4 u = *(const float4*)&qw[c0 + k * 4];
    d0 += cv[k].x * w.x + cv[k].y * w.y + cv[k].z * w.z + cv[k].w * w.w;
    d1 += cv[k].x * u.x + cv[k].y * u.y + cv[k].z * u.z + cv[k].w * u.w;
  }
  d0 += __shfl_xor(d0, 1); d0 += __shfl_xor(d0, 2); d0 += __shfl_xor(d0, 4);
  d1 += __shfl_xor(d1, 1); d1 += __shfl_xor(d1, 2); d1 += __shfl_xor(d1, 4);
  if ((t & 7) == 0) { s0[grow] = d0; s1[grow] = d1; }
#pragma unroll
  for (int k2 = 0; k2 < 4; ++k2) {
    float4 m0 = *(const float4*)&cqw[c0 + k2 * 8];
    float4 m1 = *(const float4*)&cqw[c0 + k2 * 8 + 4];
    bf16x8 vm, vq, vc;
#pragma unroll
    for (int e = 0; e < 8; ++e) {
      float cvv = ((const float*)&cv[k2 * 2 + (e >> 2)])[e & 3];
      float qvv = ((const float*)&qv[k2 * 2 + (e >> 2)])[e & 3];
      float mw = (e < 4) ? ((const float*)&m0)[e] : ((const float*)&m1)[e - 4];
      vm[e] = (bf16)(cvv * mw);
      vq[e] = (bf16)qvv;
      vc[e] = (bf16)cvv;
    }
    *(bf16x8*)&cm[base + k2 * 8] = vm;
    *(bf16x8*)&qb[base + k2 * 8] = vq;
    *(bf16x8*)&tc[rl][c0 + k2 * 8] = vc;
    *(bf16x8*)&tq[rl][c0 + k2 * 8] = vq;
  }
  __syncthreads();
  // transpose out: thread t owns d = t
  int d = t;
  size_t tb = ((size_t)b * Dn + d) * Ln + l0;
  bf16x8 o[4];
#pragma unroll
  for (int j = 0; j < 4; ++j)
#pragma unroll
    for (int e = 0; e < 8; ++e) o[j][e] = tc[j * 8 + e][d];
#pragma unroll
  for (int j = 0; j < 4; ++j) *(bf16x8*)&cT[tb + j * 8] = o[j];
#pragma unroll
  for (int j = 0; j < 4; ++j)
#pragma unroll
    for (int e = 0; e < 8; ++e) o[j][e] = tq[j * 8 + e][d];
#pragma unroll
  for (int j = 0; j < 4; ++j) *(bf16x8*)&qT[tb + j * 8] = o[j];
}

// --------- S = cm @ qb^T + s0 + s1 + bias (fp16 out), 8 waves, BK=64 ----------
__global__ __launch_bounds__(512) void g_s(const bf16* __restrict__ Am,
                                           const bf16* __restrict__ Bm,
                                           const float* __restrict__ s0,
                                           const float* __restrict__ s1,
                                           const float* __restrict__ bias,
                                           f16* __restrict__ S) {
  __shared__ __align__(16) bf16 lds[2][2 * 128 * 64];   // A+B (each 128x64), 64 KB
  int f = blockIdx.x;
  int o = (f & 7) * 128 + (f >> 3);
  int bx = o & 7, by = (o >> 3) & 7, b = o >> 6;
  const bf16* Ab = Am + (size_t)b * Ln * Dn + (size_t)by * 128 * Dn;
  const bf16* Bb = Bm + (size_t)b * Ln * Dn + (size_t)bx * 128 * Dn;
  const int tid = threadIdx.x, wid = tid >> 6, lane = tid & 63;
  const int r = lane & 15, h = lane >> 4, wr = wid >> 2, wc = wid & 3;
  f32x4 acc[4][2];
  f32x4 zero = {0.f, 0.f, 0.f, 0.f};
#pragma unroll
  for (int i = 0; i < 4; ++i)
#pragma unroll
    for (int j = 0; j < 2; ++j) acc[i][j] = zero;

  stage512(Ab, Dn, 0, &lds[0][0], tid, wid);
  stage512(Bb, Dn, 0, &lds[0][8192], tid, wid);
  for (int t = 0; t < 4; ++t) {
    int cur = t & 1;
    if (t < 3) {
      stage512(Ab, Dn, (t + 1) * 64, &lds[cur ^ 1][0], tid, wid);
      stage512(Bb, Dn, (t + 1) * 64, &lds[cur ^ 1][8192], tid, wid);
      VMCNT(4);
    } else {
      VMCNT(0);
    }
    BARR;
    const bf16* lA = &lds[cur][0];
    const bf16* lB = &lds[cur][8192];
#pragma unroll
    for (int kk2 = 0; kk2 < 2; ++kk2) {
      int slot = (kk2 << 2) | h;
      bf16x8 av[4], bv[2];
#pragma unroll
      for (int i = 0; i < 4; ++i)
        av[i] = *(const bf16x8*)swzp(lA, (wr << 6) + (i << 4) + r, slot);
#pragma unroll
      for (int j = 0; j < 2; ++j)
        bv[j] = *(const bf16x8*)swzp(lB, (wc << 5) + (j << 4) + r, slot);
#pragma unroll
      for (int i = 0; i < 4; ++i)
#pragma unroll
        for (int j = 0; j < 2; ++j)
          acc[i][j] = __builtin_amdgcn_mfma_f32_16x16x32_bf16(av[i], bv[j], acc[i][j], 0, 0, 0);
    }
    LGKM0; BARR;
  }
  int grow = by * 128 + wr * 64, gcol = bx * 128 + wc * 32;
  float bvv = bias[0];
  size_t sb = (size_t)b * Ln * Ln;
#pragma unroll
  for (int j = 0; j < 2; ++j) {
    int n = gcol + j * 16 + r;
    float v1 = s1[b * Ln + n];
#pragma unroll
    for (int i = 0; i < 4; ++i) {
      int mb = grow + i * 16 + h * 4;
#pragma unroll
      for (int g = 0; g < 4; ++g) {
        float v0 = s0[b * Ln + mb + g];
        S[sb + (size_t)(mb + g) * Ln + n] = (f16)(acc[i][j][g] + v0 + v1 + bvv);
      }
    }
  }
}

// ---- batch-axis softmax (over b) + transpose: P2[b][j][i] (bp2 only) --------
__global__ __launch_bounds__(256) void k_bp2(const f16* __restrict__ S,
                                             const float* __restrict__ cmask,
                                             bf16* __restrict__ P2) {
  __shared__ __align__(16) bf16 tile[8][32][36];   // 18 KB
  int blk = blockIdx.x;
  int t = threadIdx.x;
  int i0 = (blk >> 5) << 5, j0 = (blk & 31) << 5;
  int ti = t >> 3, tj4 = (t & 7) << 2;
  int i = i0 + ti;
  const f16* Sp = S + (size_t)i * Ln + j0 + tj4;
  float fm[16];
#pragma unroll
  for (int b = 0; b < 16; ++b) fm[b] = maskf(cmask[b * Ln + i]);
  f16x4 u[16];
#pragma unroll
  for (int b = 0; b < 16; ++b) u[b] = *(const f16x4*)(Sp + (size_t)b * Ln * Ln);
  float m[4] = {-3.4e38f, -3.4e38f, -3.4e38f, -3.4e38f};
#pragma unroll
  for (int b = 0; b < 16; ++b)
#pragma unroll
    for (int g = 0; g < 4; ++g) m[g] = fmaxf(m[g], (float)u[b][g] * fm[b]);
  float e[16][4];
  float s[4] = {0.f, 0.f, 0.f, 0.f};
#pragma unroll
  for (int b = 0; b < 16; ++b)
#pragma unroll
    for (int g = 0; g < 4; ++g) {
      e[b][g] = __expf((float)u[b][g] * fm[b] - m[g]);
      s[g] += e[b][g];
    }
#pragma unroll
  for (int g = 0; g < 4; ++g) s[g] = 1.0f / s[g];
  int jl = t >> 3, i4 = (t & 7) << 2;
#pragma unroll
  for (int half = 0; half < 2; ++half) {
    if (half) __syncthreads();   // protect tile reuse
#pragma unroll
    for (int bb = 0; bb < 8; ++bb) {
      int b = half * 8 + bb;
#pragma unroll
      for (int g = 0; g < 4; ++g) tile[bb][tj4 + g][ti] = (bf16)(e[b][g] * s[g]);
    }
    __syncthreads();
#pragma unroll
    for (int bb = 0; bb < 8; ++bb) {
      *(bf16x4*)&P2[((size_t)(half * 8 + bb) * Ln + j0 + jl) * Ln + i0 + i4] =
          *(const bf16x4*)&tile[bb][jl][i4];
    }
  }
}

// ---- merged: blocks 0..255 = TT = cT @ P2^T (128x128, 8 waves, BK=64, vmcnt);
// blocks 256..2303 = row softmax P1 (8 rows/block). Independent work that
// previously serialized; row-softmax streams while g_t blocks are
// latency-bound, using the CU's idle memory slots. ---------------------------
__global__ __launch_bounds__(512) void g_tr(const bf16* __restrict__ cT,
                                            const bf16* __restrict__ P2,
                                            bf16* __restrict__ TT,
                                            const f16* __restrict__ S,
                                            const float* __restrict__ qmask,
                                            bf16* __restrict__ P1) {
  __shared__ __align__(16) bf16 lds[2][2 * 128 * 64];   // A+B (each 128x64), 64 KB
  int blk = blockIdx.x;
  if (blk < 256) {
    int f = blk;
    int o = (f & 7) * 32 + (f >> 3);   // XCD-chunked
    int b = o >> 4, md = (o >> 3) & 1, nb = o & 7;
    const bf16* Ab = cT + (size_t)b * Dn * Ln + (size_t)md * 128 * Ln;
    const bf16* Bb = P2 + (size_t)b * Ln * Ln + (size_t)nb * 128 * Ln;
    const int tid = threadIdx.x, wid = tid >> 6, lane = tid & 63;
    const int r = lane & 15, h = lane >> 4, wr = wid >> 2, wc = wid & 3;
    f32x4 acc[4][2];
    f32x4 zero = {0.f, 0.f, 0.f, 0.f};
#pragma unroll
    for (int i = 0; i < 4; ++i)
#pragma unroll
      for (int j = 0; j < 2; ++j) acc[i][j] = zero;

    stage512(Ab, Ln, 0, &lds[0][0], tid, wid);
    stage512(Bb, Ln, 0, &lds[0][8192], tid, wid);
    for (int t = 0; t < 16; ++t) {
      int cur = t & 1;
      if (t < 15) {
        stage512(Ab, Ln, (t + 1) * 64, &lds[cur ^ 1][0], tid, wid);
        stage512(Bb, Ln, (t + 1) * 64, &lds[cur ^ 1][8192], tid, wid);
        VMCNT(4);
      } else {
        VMCNT(0);
      }
      BARR;
      const bf16* lA = &lds[cur][0];
      const bf16* lB = &lds[cur][8192];
#pragma unroll
      for (int kk2 = 0; kk2 < 2; ++kk2) {
        int slot = (kk2 << 2) | h;
        bf16x8 av[4], bv[2];
#pragma unroll
        for (int i = 0; i < 4; ++i)
          av[i] = *(const bf16x8*)swzp(lA, (wr << 6) + (i << 4) + r, slot);
#pragma unroll
        for (int j = 0; j < 2; ++j)
          bv[j] = *(const bf16x8*)swzp(lB, (wc << 5) + (j << 4) + r, slot);
#pragma unroll
        for (int i = 0; i < 4; ++i)
#pragma unroll
          for (int j = 0; j < 2; ++j)
            acc[i][j] = __builtin_amdgcn_mfma_f32_16x16x32_bf16(av[i], bv[j], acc[i][j], 0, 0, 0);
      }
      LGKM0; BARR;
    }
    size_t ob = (size_t)b * Dn * Ln;
    int dbase = md * 128 + wr * 64, cbase = nb * 128 + wc * 32;
#pragma unroll
    for (int i = 0; i < 4; ++i)
#pragma unroll
      for (int j = 0; j < 2; ++j) {
        int n = cbase + j * 16 + r;
#pragma unroll
        for (int g = 0; g < 4; ++g)
          TT[ob + (size_t)(dbase + i * 16 + h * 4 + g) * Ln + n] = (bf16)acc[i][j][g];
      }
  } else {
    // ---- row softmax: P1 = softmax_j(S * maskf(qmask_j)), 8 rows/block ----
    int t = threadIdx.x;
    int row = (blk - 256) * 8 + (t >> 6);
    int b = row >> 10;
    int lane = t & 63;
    const f16* Sr = S + (size_t)row * Ln;
    const float* qm = qmask + (size_t)b * Ln;
    float v[16];
    float mx = -3.4e38f;
#pragma unroll
    for (int p = 0; p < 2; ++p) {
      f16x8 x = ((const f16x8*)Sr)[lane + (p << 6)];
      float4 m0 = ((const float4*)qm)[(lane + (p << 6)) * 2];
      float4 m1 = ((const float4*)qm)[(lane + (p << 6)) * 2 + 1];
      float mm[8] = {m0.x, m0.y, m0.z, m0.w, m1.x, m1.y, m1.z, m1.w};
#pragma unroll
      for (int e = 0; e < 8; ++e) {
        float xv = (float)x[e] * maskf(mm[e]);
        v[8 * p + e] = xv;
        mx = fmaxf(mx, xv);
      }
    }
#pragma unroll
    for (int off = 32; off; off >>= 1) mx = fmaxf(mx, __shfl_xor(mx, off));
    float sum = 0.f;
#pragma unroll
    for (int k = 0; k < 16; ++k) {
      v[k] = __expf(v[k] - mx);
      sum += v[k];
    }
#pragma unroll
    for (int off = 32; off; off >>= 1) sum += __shfl_xor(sum, off);
    float inv = 1.0f / sum;
    bf16* Pr = P1 + (size_t)row * Ln;
#pragma unroll
    for (int p = 0; p < 2; ++p) {
      bf16x8 o;
#pragma unroll
      for (int e = 0; e < 8; ++e) o[e] = (bf16)(v[8 * p + e] * inv);
      ((bf16x8*)Pr)[lane + (p << 6)] = o;
    }
  }
}

// ------- merged: C2Q = P1 @ qT^T, Q2C = P1 @ TT^T ; chunks 0,1,2,3 -------------
// 128x128 tiles, 8 waves, BK=64, 2-buffer counted-vmcnt. Chunk0 (= c) written
// here, piggybacking on the c load already needed for o2/o3.
__global__ __launch_bounds__(512) void g_cq(const bf16* __restrict__ P1,
                                            const bf16* __restrict__ qT,
                                            const bf16* __restrict__ TT,
                                            const float* __restrict__ c,
                                            float* __restrict__ out) {
  __shared__ __align__(16) bf16 lds[2][3 * 128 * 64];   // A+B1+B2 (each 128x64), 96 KB
  int f = blockIdx.x;
  int o = (f & 7) * 32 + (f >> 3);   // 256 blocks, XCD-chunked
  int b = o >> 4, by = (o >> 1) & 7, bx = o & 1;
  const bf16* Ab = P1 + (size_t)b * Ln * Ln + (size_t)by * 128 * Ln;
  const bf16* B1 = qT + (size_t)b * Dn * Ln + (size_t)bx * 128 * Ln;
  const bf16* B2 = TT + (size_t)b * Dn * Ln + (size_t)bx * 128 * Ln;
  const int tid = threadIdx.x, wid = tid >> 6, lane = tid & 63;
  const int r = lane & 15, h = lane >> 4, wr = wid >> 2, wc = wid & 3;
  f32x4 acc1[4][2], acc2[4][2];
  f32x4 zero = {0.f, 0.f, 0.f, 0.f};
#pragma unroll
  for (int i = 0; i < 4; ++i)
#pragma unroll
    for (int j = 0; j < 2; ++j) { acc1[i][j] = zero; acc2[i][j] = zero; }

  stage512(Ab, Ln, 0, &lds[0][0], tid, wid);
  stage512(B1, Ln, 0, &lds[0][8192], tid, wid);
  stage512(B2, Ln, 0, &lds[0][16384], tid, wid);
  for (int t = 0; t < 16; ++t) {
    int cur = t & 1;
    if (t < 15) {
      stage512(Ab, Ln, (t + 1) * 64, &lds[cur ^ 1][0], tid, wid);
      stage512(B1, Ln, (t + 1) * 64, &lds[cur ^ 1][8192], tid, wid);
      stage512(B2, Ln, (t + 1) * 64, &lds[cur ^ 1][16384], tid, wid);
      VMCNT(6);
    } else {
      VMCNT(0);
    }
    BARR;
    const bf16* lA = &lds[cur][0];
    const bf16* lB1 = &lds[cur][8192];
    const bf16* lB2 = &lds[cur][16384];
#pragma unroll
    for (int kk2 = 0; kk2 < 2; ++kk2) {
      int slot = (kk2 << 2) | h;
      bf16x8 av[4], bv[2];
#pragma unroll
      for (int i = 0; i < 4; ++i)
        av[i] = *(const bf16x8*)swzp(lA, (wr << 6) + (i << 4) + r, slot);
#pragma unroll
      for (int j = 0; j < 2; ++j)
        bv[j] = *(const bf16x8*)swzp(lB1, (wc << 5) + (j << 4) + r, slot);
#pragma unroll
      for (int i = 0; i < 4; ++i)
#pragma unroll
        for (int j = 0; j < 2; ++j)
          acc1[i][j] = __builtin_amdgcn_mfma_f32_16x16x32_bf16(av[i], bv[j], acc1[i][j], 0, 0, 0);
#pragma unroll
      for (int j = 0; j < 2; ++j)
        bv[j] = *(const bf16x8*)swzp(lB2, (wc << 5) + (j << 4) + r, slot);
#pragma unroll
      for (int i = 0; i < 4; ++i)
#pragma unroll
        for (int j = 0; j < 2; ++j)
          acc2[i][j] = __builtin_amdgcn_mfma_f32_16x16x32_bf16(av[i], bv[j], acc2[i][j], 0, 0, 0);
    }
    LGKM0; BARR;
  }

  int grow = by * 128 + wr * 64, gcol = bx * 128 + wc * 32;
  const float* cb = c + (size_t)b * Ln * Dn;
  float* o0 = out + (size_t)(0 * Bn + b) * Ln * Dn;
  float* o1 = out + (size_t)(1 * Bn + b) * Ln * Dn;
  float* o2 = out + (size_t)(2 * Bn + b) * Ln * Dn;
  float* o3 = out + (size_t)(3 * Bn + b) * Ln * Dn;
#pragma unroll
  for (int j = 0; j < 2; ++j) {
    int n = gcol + j * 16 + r;
#pragma unroll
    for (int i = 0; i < 4; ++i) {
      int mb = grow + i * 16 + h * 4;
#pragma unroll
      for (int g = 0; g < 4; ++g) {
        float v1 = acc1[i][j][g];
        float v2 = acc2[i][j][g];
        size_t off = (size_t)(mb + g) * Dn + n;
        float cc = cb[off];
        o0[off] = cc;
        o1[off] = v1;
        o2[off] = cc * v1;
        o3[off] = cc * v2;
      }
    }
  }
}

extern "C" void kernel_launch(void* const* d_in, const int* in_sizes, int n_in,
                              void* d_out, int out_size, void* d_ws, size_t ws_size,
                              hipStream_t stream) {
  const float* c = (const float*)d_in[0];
  const float* q = (const float*)d_in[1];
  const float* cmask = (const float*)d_in[2];
  const float* qmask = (const float*)d_in[3];
  const float* cw = (const float*)d_in[4];
  const float* qw = (const float*)d_in[5];
  const float* cqw = (const float*)d_in[6];
  const float* bias = (const float*)d_in[7];
  float* out = (float*)d_out;

  char* w = (char*)d_ws;
  f16* S = (f16*)w;       w += (size_t)Bn * Ln * Ln * 2;
  bf16* P1 = (bf16*)w;    w += (size_t)Bn * Ln * Ln * 2;
  bf16* P2 = (bf16*)w;    w += (size_t)Bn * Ln * Ln * 2;
  bf16* cm = (bf16*)w;    w += (size_t)Bn * Ln * Dn * 2;
  bf16* qb = (bf16*)w;    w += (size_t)Bn * Ln * Dn * 2;
  bf16* cT = (bf16*)w;    w += (size_t)Bn * Dn * Ln * 2;
  bf16* qT = (bf16*)w;    w += (size_t)Bn * Dn * Ln * 2;
  bf16* TT = (bf16*)w;    w += (size_t)Bn * Dn * Ln * 2;
  float* s0 = (float*)w;  w += (size_t)Bn * Ln * 4;
  float* s1 = (float*)w;  w += (size_t)Bn * Ln * 4;
  if ((size_t)(w - (char*)d_ws) > ws_size) return;  // ws too small: fail visibly

  k_prep2<<<dim3(Bn * Ln / 32), 256, 0, stream>>>(c, q, cw, qw, cqw, cm, qb, cT, qT, s0, s1);
  g_s<<<dim3(1024), 512, 0, stream>>>(cm, qb, s0, s1, bias, S);
  k_bp2<<<dim3(Ln / 32 * (Ln / 32)), 256, 0, stream>>>(S, cmask, P2);
  g_tr<<<dim3(256 + Bn * Ln / 8), 512, 0, stream>>>(cT, P2, TT, S, qmask, P1);
  g_cq<<<dim3(256), 512, 0, stream>>>(P1, qT, TT, c, out);
}

// Round 14
// 111.064 us; speedup vs baseline: 1.0095x; 1.0095x over previous
//
#include <hip/hip_runtime.h>

typedef __bf16 bf16;
typedef _Float16 f16;
typedef __attribute__((ext_vector_type(8))) __bf16 bf16x8;
typedef __attribute__((ext_vector_type(4))) __bf16 bf16x4;
typedef __attribute__((ext_vector_type(8))) _Float16 f16x8;
typedef __attribute__((ext_vector_type(4))) _Float16 f16x4;
typedef __attribute__((ext_vector_type(4))) float f32x4;

constexpr int Bn = 16, Ln = 1024, Dn = 256;

__device__ __forceinline__ float maskf(float m) { return m + (1.0f - m) * 1e30f; }

__device__ __forceinline__ void gload16(const void* g, void* l) {
  __builtin_amdgcn_global_load_lds((const __attribute__((address_space(1))) void*)g,
                                   (__attribute__((address_space(3))) void*)l, 16, 0, 0);
}

// counted-waitcnt pipeline primitives (T4). BARR = compiler-fenced hw barrier.
#define VMCNT(N) asm volatile("s_waitcnt vmcnt(" #N ")" ::: "memory")
#define LGKM0 asm volatile("s_waitcnt lgkmcnt(0)" ::: "memory")
#define BARR                                  \
  do {                                        \
    asm volatile("" ::: "memory");            \
    __builtin_amdgcn_s_barrier();             \
    asm volatile("" ::: "memory");            \
  } while (0)

// ---- 512-thread staging: 128 rows x 64 k tile; pre-swizzle GLOBAL source
// (slot ^= row&7) so LDS dst stays linear (rule #21); read-side XOR restores
// conflict-free banking. ----
__device__ __forceinline__ void stage512(const bf16* __restrict__ G, int ldg, int k0,
                                         bf16* L, int tid, int wid) {
#pragma unroll
  for (int p = 0; p < 2; ++p) {                     // 128 rows x 64 k
    int u = tid + (p << 9);
    int row = u >> 3, s = u & 7;
    int kk = ((s ^ (row & 7)) << 3);
    gload16(G + (size_t)row * ldg + k0 + kk, L + ((p << 9) + (wid << 6)) * 8);
  }
}

// swizzled read address within a 64-col (128B-row) LDS tile
__device__ __forceinline__ const bf16* swzp(const bf16* L, int row, int slot) {
  return L + row * 64 + ((slot ^ (row & 7)) << 3);
}

// ---------------- fused prep: dots s0,s1; cm=bf16(c*cqw); qb=bf16(q);
// cT,qT transposed bf16. (chunk0 copy of c lives in g_cq's epilogue.) -------
__global__ __launch_bounds__(256) void k_prep2(
    const float* __restrict__ c, const float* __restrict__ q,
    const float* __restrict__ cw, const float* __restrict__ qw,
    const float* __restrict__ cqw, bf16* __restrict__ cm, bf16* __restrict__ qb,
    bf16* __restrict__ cT, bf16* __restrict__ qT,
    float* __restrict__ s0, float* __restrict__ s1) {
  __shared__ __align__(16) bf16 tc[32][264];
  __shared__ __align__(16) bf16 tq[32][264];
  int blk = blockIdx.x;          // 512 blocks
  int b = blk >> 5;
  int l0 = (blk & 31) << 5;
  int t = threadIdx.x;
  int rl = t >> 3;               // local row 0..31
  int c0 = (t & 7) << 5;         // col start (32 cols/thread)
  int grow = b * Ln + l0 + rl;
  size_t base = (size_t)grow * Dn + c0;
  float4 cv[8], qv[8];
#pragma unroll
  for (int k = 0; k < 8; ++k) {
    cv[k] = *(const float4*)&c[base + k * 4];
    qv[k] = *(const float4*)&q[base + k * 4];
  }
  float d0 = 0.f, d1 = 0.f;
#pragma unroll
  for (int k = 0; k < 8; ++k) {
    float4 w = *(const float4*)&cw[c0 + k * 4];
    float4 u = *(const float4*)&qw[c0 + k * 4];
    d0 += cv[k].x * w.x + cv[k].y * w.y + cv[k].z * w.z + cv[k].w * w.w;
    d1 += cv[k].x * u.x + cv[k].y * u.y + cv[k].z * u.z + cv[k].w * u.w;
  }
  d0 += __shfl_xor(d0, 1); d0 += __shfl_xor(d0, 2); d0 += __shfl_xor(d0, 4);
  d1 += __shfl_xor(d1, 1); d1 += __shfl_xor(d1, 2); d1 += __shfl_xor(d1, 4);
  if ((t & 7) == 0) { s0[grow] = d0; s1[grow] = d1; }
#pragma unroll
  for (int k2 = 0; k2 < 4; ++k2) {
    float4 m0 = *(const float4*)&cqw[c0 + k2 * 8];
    float4 m1 = *(const float4*)&cqw[c0 + k2 * 8 + 4];
    bf16x8 vm, vq, vc;
#pragma unroll
    for (int e = 0; e < 8; ++e) {
      float cvv = ((const float*)&cv[k2 * 2 + (e >> 2)])[e & 3];
      float qvv = ((const float*)&qv[k2 * 2 + (e >> 2)])[e & 3];
      float mw = (e < 4) ? ((const float*)&m0)[e] : ((const float*)&m1)[e - 4];
      vm[e] = (bf16)(cvv * mw);
      vq[e] = (bf16)qvv;
      vc[e] = (bf16)cvv;
    }
    *(bf16x8*)&cm[base + k2 * 8] = vm;
    *(bf16x8*)&qb[base + k2 * 8] = vq;
    *(bf16x8*)&tc[rl][c0 + k2 * 8] = vc;
    *(bf16x8*)&tq[rl][c0 + k2 * 8] = vq;
  }
  __syncthreads();
  // transpose out: thread t owns d = t
  int d = t;
  size_t tb = ((size_t)b * Dn + d) * Ln + l0;
  bf16x8 o[4];
#pragma unroll
  for (int j = 0; j < 4; ++j)
#pragma unroll
    for (int e = 0; e < 8; ++e) o[j][e] = tc[j * 8 + e][d];
#pragma unroll
  for (int j = 0; j < 4; ++j) *(bf16x8*)&cT[tb + j * 8] = o[j];
#pragma unroll
  for (int j = 0; j < 4; ++j)
#pragma unroll
    for (int e = 0; e < 8; ++e) o[j][e] = tq[j * 8 + e][d];
#pragma unroll
  for (int j = 0; j < 4; ++j) *(bf16x8*)&qT[tb + j * 8] = o[j];
}

// --------- S = cm @ qb^T + s0 + s1 + bias (fp16 out), 8 waves, BK=64 ----------
__global__ __launch_bounds__(512) void g_s(const bf16* __restrict__ Am,
                                           const bf16* __restrict__ Bm,
                                           const float* __restrict__ s0,
                                           const float* __restrict__ s1,
                                           const float* __restrict__ bias,
                                           f16* __restrict__ S) {
  __shared__ __align__(16) bf16 lds[2][2 * 128 * 64];   // A+B (each 128x64), 64 KB
  int f = blockIdx.x;
  int o = (f & 7) * 128 + (f >> 3);
  int bx = o & 7, by = (o >> 3) & 7, b = o >> 6;
  const bf16* Ab = Am + (size_t)b * Ln * Dn + (size_t)by * 128 * Dn;
  const bf16* Bb = Bm + (size_t)b * Ln * Dn + (size_t)bx * 128 * Dn;
  const int tid = threadIdx.x, wid = tid >> 6, lane = tid & 63;
  const int r = lane & 15, h = lane >> 4, wr = wid >> 2, wc = wid & 3;
  f32x4 acc[4][2];
  f32x4 zero = {0.f, 0.f, 0.f, 0.f};
#pragma unroll
  for (int i = 0; i < 4; ++i)
#pragma unroll
    for (int j = 0; j < 2; ++j) acc[i][j] = zero;

  stage512(Ab, Dn, 0, &lds[0][0], tid, wid);
  stage512(Bb, Dn, 0, &lds[0][8192], tid, wid);
  for (int t = 0; t < 4; ++t) {
    int cur = t & 1;
    if (t < 3) {
      stage512(Ab, Dn, (t + 1) * 64, &lds[cur ^ 1][0], tid, wid);
      stage512(Bb, Dn, (t + 1) * 64, &lds[cur ^ 1][8192], tid, wid);
      VMCNT(4);
    } else {
      VMCNT(0);
    }
    BARR;
    const bf16* lA = &lds[cur][0];
    const bf16* lB = &lds[cur][8192];
#pragma unroll
    for (int kk2 = 0; kk2 < 2; ++kk2) {
      int slot = (kk2 << 2) | h;
      bf16x8 av[4], bv[2];
#pragma unroll
      for (int i = 0; i < 4; ++i)
        av[i] = *(const bf16x8*)swzp(lA, (wr << 6) + (i << 4) + r, slot);
#pragma unroll
      for (int j = 0; j < 2; ++j)
        bv[j] = *(const bf16x8*)swzp(lB, (wc << 5) + (j << 4) + r, slot);
#pragma unroll
      for (int i = 0; i < 4; ++i)
#pragma unroll
        for (int j = 0; j < 2; ++j)
          acc[i][j] = __builtin_amdgcn_mfma_f32_16x16x32_bf16(av[i], bv[j], acc[i][j], 0, 0, 0);
    }
    LGKM0; BARR;
  }
  int grow = by * 128 + wr * 64, gcol = bx * 128 + wc * 32;
  float bvv = bias[0];
  size_t sb = (size_t)b * Ln * Ln;
#pragma unroll
  for (int j = 0; j < 2; ++j) {
    int n = gcol + j * 16 + r;
    float v1 = s1[b * Ln + n];
#pragma unroll
    for (int i = 0; i < 4; ++i) {
      int mb = grow + i * 16 + h * 4;
#pragma unroll
      for (int g = 0; g < 4; ++g) {
        float v0 = s0[b * Ln + mb + g];
        S[sb + (size_t)(mb + g) * Ln + n] = (f16)(acc[i][j][g] + v0 + v1 + bvv);
      }
    }
  }
}

// ---- merged softmax dispatch: blocks 0..1023 = batch-softmax+transpose (bp2,
// 18 KB two-pass tile -> 8 blocks/CU for whole dispatch), blocks 1024..5119 =
// row softmax. Both read only S. ---------------------------------------------
__global__ __launch_bounds__(256) void k_sm(const f16* __restrict__ S,
                                            const float* __restrict__ qmask,
                                            const float* __restrict__ cmask,
                                            bf16* __restrict__ P1,
                                            bf16* __restrict__ P2) {
  __shared__ __align__(16) bf16 tile[8][32][36];   // 18 KB (bp2 blocks only)
  int blk = blockIdx.x;
  int t = threadIdx.x;
  if (blk < 1024) {
    // ---- batch-axis softmax (over b) + transpose: P2[b][j][i] ----
    int i0 = (blk >> 5) << 5, j0 = (blk & 31) << 5;
    int ti = t >> 3, tj4 = (t & 7) << 2;
    int i = i0 + ti;
    const f16* Sp = S + (size_t)i * Ln + j0 + tj4;
    float fm[16];
#pragma unroll
    for (int b = 0; b < 16; ++b) fm[b] = maskf(cmask[b * Ln + i]);
    f16x4 u[16];
#pragma unroll
    for (int b = 0; b < 16; ++b) u[b] = *(const f16x4*)(Sp + (size_t)b * Ln * Ln);
    float m[4] = {-3.4e38f, -3.4e38f, -3.4e38f, -3.4e38f};
#pragma unroll
    for (int b = 0; b < 16; ++b)
#pragma unroll
      for (int g = 0; g < 4; ++g) m[g] = fmaxf(m[g], (float)u[b][g] * fm[b]);
    float e[16][4];
    float s[4] = {0.f, 0.f, 0.f, 0.f};
#pragma unroll
    for (int b = 0; b < 16; ++b)
#pragma unroll
      for (int g = 0; g < 4; ++g) {
        e[b][g] = __expf((float)u[b][g] * fm[b] - m[g]);
        s[g] += e[b][g];
      }
#pragma unroll
    for (int g = 0; g < 4; ++g) s[g] = 1.0f / s[g];
    int jl = t >> 3, i4 = (t & 7) << 2;
#pragma unroll
    for (int half = 0; half < 2; ++half) {
      if (half) __syncthreads();   // protect tile reuse
#pragma unroll
      for (int bb = 0; bb < 8; ++bb) {
        int b = half * 8 + bb;
#pragma unroll
        for (int g = 0; g < 4; ++g) tile[bb][tj4 + g][ti] = (bf16)(e[b][g] * s[g]);
      }
      __syncthreads();
#pragma unroll
      for (int bb = 0; bb < 8; ++bb) {
        *(bf16x4*)&P2[((size_t)(half * 8 + bb) * Ln + j0 + jl) * Ln + i0 + i4] =
            *(const bf16x4*)&tile[bb][jl][i4];
      }
    }
  } else {
    // ---- row softmax: P1 = softmax_j(S * maskf(qmask_j)) ----
    int row = (blk - 1024) * 4 + (t >> 6);
    int b = row >> 10;
    int lane = t & 63;
    const f16* Sr = S + (size_t)row * Ln;
    const float* qm = qmask + (size_t)b * Ln;
    float v[16];
    float mx = -3.4e38f;
#pragma unroll
    for (int p = 0; p < 2; ++p) {
      f16x8 x = ((const f16x8*)Sr)[lane + (p << 6)];
      float4 m0 = ((const float4*)qm)[(lane + (p << 6)) * 2];
      float4 m1 = ((const float4*)qm)[(lane + (p << 6)) * 2 + 1];
      float mm[8] = {m0.x, m0.y, m0.z, m0.w, m1.x, m1.y, m1.z, m1.w};
#pragma unroll
      for (int e = 0; e < 8; ++e) {
        float xv = (float)x[e] * maskf(mm[e]);
        v[8 * p + e] = xv;
        mx = fmaxf(mx, xv);
      }
    }
#pragma unroll
    for (int off = 32; off; off >>= 1) mx = fmaxf(mx, __shfl_xor(mx, off));
    float sum = 0.f;
#pragma unroll
    for (int k = 0; k < 16; ++k) {
      v[k] = __expf(v[k] - mx);
      sum += v[k];
    }
#pragma unroll
    for (int off = 32; off; off >>= 1) sum += __shfl_xor(sum, off);
    float inv = 1.0f / sum;
    bf16* Pr = P1 + (size_t)row * Ln;
#pragma unroll
    for (int p = 0; p < 2; ++p) {
      bf16x8 o;
#pragma unroll
      for (int e = 0; e < 8; ++e) o[e] = (bf16)(v[8 * p + e] * inv);
      ((bf16x8*)Pr)[lane + (p << 6)] = o;
    }
  }
}

// ------- TT[b][d][jq] = cT @ P2^T  (128x128 tiles, 8 waves, BK=64, vmcnt) ------
__global__ __launch_bounds__(512) void g_t(const bf16* __restrict__ cT,
                                           const bf16* __restrict__ P2,
                                           bf16* __restrict__ TT) {
  __shared__ __align__(16) bf16 lds[2][2 * 128 * 64];   // A+B (each 128x64), 64 KB
  int f = blockIdx.x;
  int o = (f & 7) * 32 + (f >> 3);   // 256 blocks, XCD-chunked
  int b = o >> 4, md = (o >> 3) & 1, nb = o & 7;
  const bf16* Ab = cT + (size_t)b * Dn * Ln + (size_t)md * 128 * Ln;
  const bf16* Bb = P2 + (size_t)b * Ln * Ln + (size_t)nb * 128 * Ln;
  const int tid = threadIdx.x, wid = tid >> 6, lane = tid & 63;
  const int r = lane & 15, h = lane >> 4, wr = wid >> 2, wc = wid & 3;
  f32x4 acc[4][2];
  f32x4 zero = {0.f, 0.f, 0.f, 0.f};
#pragma unroll
  for (int i = 0; i < 4; ++i)
#pragma unroll
    for (int j = 0; j < 2; ++j) acc[i][j] = zero;

  stage512(Ab, Ln, 0, &lds[0][0], tid, wid);
  stage512(Bb, Ln, 0, &lds[0][8192], tid, wid);
  for (int t = 0; t < 16; ++t) {
    int cur = t & 1;
    if (t < 15) {
      stage512(Ab, Ln, (t + 1) * 64, &lds[cur ^ 1][0], tid, wid);
      stage512(Bb, Ln, (t + 1) * 64, &lds[cur ^ 1][8192], tid, wid);
      VMCNT(4);
    } else {
      VMCNT(0);
    }
    BARR;
    const bf16* lA = &lds[cur][0];
    const bf16* lB = &lds[cur][8192];
#pragma unroll
    for (int kk2 = 0; kk2 < 2; ++kk2) {
      int slot = (kk2 << 2) | h;
      bf16x8 av[4], bv[2];
#pragma unroll
      for (int i = 0; i < 4; ++i)
        av[i] = *(const bf16x8*)swzp(lA, (wr << 6) + (i << 4) + r, slot);
#pragma unroll
      for (int j = 0; j < 2; ++j)
        bv[j] = *(const bf16x8*)swzp(lB, (wc << 5) + (j << 4) + r, slot);
#pragma unroll
      for (int i = 0; i < 4; ++i)
#pragma unroll
        for (int j = 0; j < 2; ++j)
          acc[i][j] = __builtin_amdgcn_mfma_f32_16x16x32_bf16(av[i], bv[j], acc[i][j], 0, 0, 0);
    }
    LGKM0; BARR;
  }
  size_t ob = (size_t)b * Dn * Ln;
  int dbase = md * 128 + wr * 64, cbase = nb * 128 + wc * 32;
#pragma unroll
  for (int i = 0; i < 4; ++i)
#pragma unroll
    for (int j = 0; j < 2; ++j) {
      int n = cbase + j * 16 + r;
#pragma unroll
      for (int g = 0; g < 4; ++g)
        TT[ob + (size_t)(dbase + i * 16 + h * 4 + g) * Ln + n] = (bf16)acc[i][j][g];
    }
}

// ------- merged: C2Q = P1 @ qT^T, Q2C = P1 @ TT^T ; chunks 0,1,2,3 -------------
// 128x128 tiles, 8 waves, BK=64, 2-buffer counted-vmcnt. Chunk0 (= c) written
// here, piggybacking on the c load already needed for o2/o3.
__global__ __launch_bounds__(512) void g_cq(const bf16* __restrict__ P1,
                                            const bf16* __restrict__ qT,
                                            const bf16* __restrict__ TT,
                                            const float* __restrict__ c,
                                            float* __restrict__ out) {
  __shared__ __align__(16) bf16 lds[2][3 * 128 * 64];   // A+B1+B2 (each 128x64), 96 KB
  int f = blockIdx.x;
  int o = (f & 7) * 32 + (f >> 3);   // 256 blocks, XCD-chunked
  int b = o >> 4, by = (o >> 1) & 7, bx = o & 1;
  const bf16* Ab = P1 + (size_t)b * Ln * Ln + (size_t)by * 128 * Ln;
  const bf16* B1 = qT + (size_t)b * Dn * Ln + (size_t)bx * 128 * Ln;
  const bf16* B2 = TT + (size_t)b * Dn * Ln + (size_t)bx * 128 * Ln;
  const int tid = threadIdx.x, wid = tid >> 6, lane = tid & 63;
  const int r = lane & 15, h = lane >> 4, wr = wid >> 2, wc = wid & 3;
  f32x4 acc1[4][2], acc2[4][2];
  f32x4 zero = {0.f, 0.f, 0.f, 0.f};
#pragma unroll
  for (int i = 0; i < 4; ++i)
#pragma unroll
    for (int j = 0; j < 2; ++j) { acc1[i][j] = zero; acc2[i][j] = zero; }

  stage512(Ab, Ln, 0, &lds[0][0], tid, wid);
  stage512(B1, Ln, 0, &lds[0][8192], tid, wid);
  stage512(B2, Ln, 0, &lds[0][16384], tid, wid);
  for (int t = 0; t < 16; ++t) {
    int cur = t & 1;
    if (t < 15) {
      stage512(Ab, Ln, (t + 1) * 64, &lds[cur ^ 1][0], tid, wid);
      stage512(B1, Ln, (t + 1) * 64, &lds[cur ^ 1][8192], tid, wid);
      stage512(B2, Ln, (t + 1) * 64, &lds[cur ^ 1][16384], tid, wid);
      VMCNT(6);
    } else {
      VMCNT(0);
    }
    BARR;
    const bf16* lA = &lds[cur][0];
    const bf16* lB1 = &lds[cur][8192];
    const bf16* lB2 = &lds[cur][16384];
#pragma unroll
    for (int kk2 = 0; kk2 < 2; ++kk2) {
      int slot = (kk2 << 2) | h;
      bf16x8 av[4], bv[2];
#pragma unroll
      for (int i = 0; i < 4; ++i)
        av[i] = *(const bf16x8*)swzp(lA, (wr << 6) + (i << 4) + r, slot);
#pragma unroll
      for (int j = 0; j < 2; ++j)
        bv[j] = *(const bf16x8*)swzp(lB1, (wc << 5) + (j << 4) + r, slot);
#pragma unroll
      for (int i = 0; i < 4; ++i)
#pragma unroll
        for (int j = 0; j < 2; ++j)
          acc1[i][j] = __builtin_amdgcn_mfma_f32_16x16x32_bf16(av[i], bv[j], acc1[i][j], 0, 0, 0);
#pragma unroll
      for (int j = 0; j < 2; ++j)
        bv[j] = *(const bf16x8*)swzp(lB2, (wc << 5) + (j << 4) + r, slot);
#pragma unroll
      for (int i = 0; i < 4; ++i)
#pragma unroll
        for (int j = 0; j < 2; ++j)
          acc2[i][j] = __builtin_amdgcn_mfma_f32_16x16x32_bf16(av[i], bv[j], acc2[i][j], 0, 0, 0);
    }
    LGKM0; BARR;
  }

  int grow = by * 128 + wr * 64, gcol = bx * 128 + wc * 32;
  const float* cb = c + (size_t)b * Ln * Dn;
  float* o0 = out + (size_t)(0 * Bn + b) * Ln * Dn;
  float* o1 = out + (size_t)(1 * Bn + b) * Ln * Dn;
  float* o2 = out + (size_t)(2 * Bn + b) * Ln * Dn;
  float* o3 = out + (size_t)(3 * Bn + b) * Ln * Dn;
#pragma unroll
  for (int j = 0; j < 2; ++j) {
    int n = gcol + j * 16 + r;
#pragma unroll
    for (int i = 0; i < 4; ++i) {
      int mb = grow + i * 16 + h * 4;
#pragma unroll
      for (int g = 0; g < 4; ++g) {
        float v1 = acc1[i][j][g];
        float v2 = acc2[i][j][g];
        size_t off = (size_t)(mb + g) * Dn + n;
        float cc = cb[off];
        o0[off] = cc;
        o1[off] = v1;
        o2[off] = cc * v1;
        o3[off] = cc * v2;
      }
    }
  }
}

extern "C" void kernel_launch(void* const* d_in, const int* in_sizes, int n_in,
                              void* d_out, int out_size, void* d_ws, size_t ws_size,
                              hipStream_t stream) {
  const float* c = (const float*)d_in[0];
  const float* q = (const float*)d_in[1];
  const float* cmask = (const float*)d_in[2];
  const float* qmask = (const float*)d_in[3];
  const float* cw = (const float*)d_in[4];
  const float* qw = (const float*)d_in[5];
  const float* cqw = (const float*)d_in[6];
  const float* bias = (const float*)d_in[7];
  float* out = (float*)d_out;

  char* w = (char*)d_ws;
  f16* S = (f16*)w;       w += (size_t)Bn * Ln * Ln * 2;
  bf16* P1 = (bf16*)w;    w += (size_t)Bn * Ln * Ln * 2;
  bf16* P2 = (bf16*)w;    w += (size_t)Bn * Ln * Ln * 2;
  bf16* cm = (bf16*)w;    w += (size_t)Bn * Ln * Dn * 2;
  bf16* qb = (bf16*)w;    w += (size_t)Bn * Ln * Dn * 2;
  bf16* cT = (bf16*)w;    w += (size_t)Bn * Dn * Ln * 2;
  bf16* qT = (bf16*)w;    w += (size_t)Bn * Dn * Ln * 2;
  bf16* TT = (bf16*)w;    w += (size_t)Bn * Dn * Ln * 2;
  float* s0 = (float*)w;  w += (size_t)Bn * Ln * 4;
  float* s1 = (float*)w;  w += (size_t)Bn * Ln * 4;
  if ((size_t)(w - (char*)d_ws) > ws_size) return;  // ws too small: fail visibly

  k_prep2<<<dim3(Bn * Ln / 32), 256, 0, stream>>>(c, q, cw, qw, cqw, cm, qb, cT, qT, s0, s1);
  g_s<<<dim3(1024), 512, 0, stream>>>(cm, qb, s0, s1, bias, S);
  k_sm<<<dim3(1024 + Bn * Ln / 4), 256, 0, stream>>>(S, qmask, cmask, P1, P2);
  g_t<<<dim3(256), 512, 0, stream>>>(cT, P2, TT);
  g_cq<<<dim3(256), 512, 0, stream>>>(P1, qT, TT, c, out);
}

// Round 15
// 110.555 us; speedup vs baseline: 1.0142x; 1.0046x over previous
//
#include <hip/hip_runtime.h>

typedef __bf16 bf16;
typedef _Float16 f16;
typedef __attribute__((ext_vector_type(8))) __bf16 bf16x8;
typedef __attribute__((ext_vector_type(4))) __bf16 bf16x4;
typedef __attribute__((ext_vector_type(8))) _Float16 f16x8;
typedef __attribute__((ext_vector_type(4))) _Float16 f16x4;
typedef __attribute__((ext_vector_type(4))) float f32x4;

constexpr int Bn = 16, Ln = 1024, Dn = 256;

__device__ __forceinline__ float maskf(float m) { return m + (1.0f - m) * 1e30f; }

__device__ __forceinline__ void gload16(const void* g, void* l) {
  __builtin_amdgcn_global_load_lds((const __attribute__((address_space(1))) void*)g,
                                   (__attribute__((address_space(3))) void*)l, 16, 0, 0);
}

// counted-waitcnt pipeline primitives (T4). BARR = compiler-fenced hw barrier.
#define VMCNT(N) asm volatile("s_waitcnt vmcnt(" #N ")" ::: "memory")
#define LGKM0 asm volatile("s_waitcnt lgkmcnt(0)" ::: "memory")
#define BARR                                  \
  do {                                        \
    asm volatile("" ::: "memory");            \
    __builtin_amdgcn_s_barrier();             \
    asm volatile("" ::: "memory");            \
  } while (0)

// ---- 512-thread staging: 128 rows x 64 k tile; pre-swizzle GLOBAL source
// (slot ^= row&7) so LDS dst stays linear (rule #21); read-side XOR restores
// conflict-free banking. ----
__device__ __forceinline__ void stage512(const bf16* __restrict__ G, int ldg, int k0,
                                         bf16* L, int tid, int wid) {
#pragma unroll
  for (int p = 0; p < 2; ++p) {                     // 128 rows x 64 k
    int u = tid + (p << 9);
    int row = u >> 3, s = u & 7;
    int kk = ((s ^ (row & 7)) << 3);
    gload16(G + (size_t)row * ldg + k0 + kk, L + ((p << 9) + (wid << 6)) * 8);
  }
}

// swizzled read address within a 64-col (128B-row) LDS tile
__device__ __forceinline__ const bf16* swzp(const bf16* L, int row, int slot) {
  return L + row * 64 + ((slot ^ (row & 7)) << 3);
}

// ---------------- fused prep: dots s0,s1; cm=bf16(c*cqw); qb=bf16(q);
// cT,qT transposed bf16. (chunk0 copy of c lives in g_cq's epilogue.) -------
__global__ __launch_bounds__(256) void k_prep2(
    const float* __restrict__ c, const float* __restrict__ q,
    const float* __restrict__ cw, const float* __restrict__ qw,
    const float* __restrict__ cqw, bf16* __restrict__ cm, bf16* __restrict__ qb,
    bf16* __restrict__ cT, bf16* __restrict__ qT,
    float* __restrict__ s0, float* __restrict__ s1) {
  __shared__ __align__(16) bf16 tc[32][264];
  __shared__ __align__(16) bf16 tq[32][264];
  int blk = blockIdx.x;          // 512 blocks
  int b = blk >> 5;
  int l0 = (blk & 31) << 5;
  int t = threadIdx.x;
  int rl = t >> 3;               // local row 0..31
  int c0 = (t & 7) << 5;         // col start (32 cols/thread)
  int grow = b * Ln + l0 + rl;
  size_t base = (size_t)grow * Dn + c0;
  float4 cv[8], qv[8];
#pragma unroll
  for (int k = 0; k < 8; ++k) {
    cv[k] = *(const float4*)&c[base + k * 4];
    qv[k] = *(const float4*)&q[base + k * 4];
  }
  float d0 = 0.f, d1 = 0.f;
#pragma unroll
  for (int k = 0; k < 8; ++k) {
    float4 w = *(const float4*)&cw[c0 + k * 4];
    float4 u = *(const float4*)&qw[c0 + k * 4];
    d0 += cv[k].x * w.x + cv[k].y * w.y + cv[k].z * w.z + cv[k].w * w.w;
    d1 += cv[k].x * u.x + cv[k].y * u.y + cv[k].z * u.z + cv[k].w * u.w;
  }
  d0 += __shfl_xor(d0, 1); d0 += __shfl_xor(d0, 2); d0 += __shfl_xor(d0, 4);
  d1 += __shfl_xor(d1, 1); d1 += __shfl_xor(d1, 2); d1 += __shfl_xor(d1, 4);
  if ((t & 7) == 0) { s0[grow] = d0; s1[grow] = d1; }
#pragma unroll
  for (int k2 = 0; k2 < 4; ++k2) {
    float4 m0 = *(const float4*)&cqw[c0 + k2 * 8];
    float4 m1 = *(const float4*)&cqw[c0 + k2 * 8 + 4];
    bf16x8 vm, vq, vc;
#pragma unroll
    for (int e = 0; e < 8; ++e) {
      float cvv = ((const float*)&cv[k2 * 2 + (e >> 2)])[e & 3];
      float qvv = ((const float*)&qv[k2 * 2 + (e >> 2)])[e & 3];
      float mw = (e < 4) ? ((const float*)&m0)[e] : ((const float*)&m1)[e - 4];
      vm[e] = (bf16)(cvv * mw);
      vq[e] = (bf16)qvv;
      vc[e] = (bf16)cvv;
    }
    *(bf16x8*)&cm[base + k2 * 8] = vm;
    *(bf16x8*)&qb[base + k2 * 8] = vq;
    *(bf16x8*)&tc[rl][c0 + k2 * 8] = vc;
    *(bf16x8*)&tq[rl][c0 + k2 * 8] = vq;
  }
  __syncthreads();
  // transpose out: thread t owns d = t
  int d = t;
  size_t tb = ((size_t)b * Dn + d) * Ln + l0;
  bf16x8 o[4];
#pragma unroll
  for (int j = 0; j < 4; ++j)
#pragma unroll
    for (int e = 0; e < 8; ++e) o[j][e] = tc[j * 8 + e][d];
#pragma unroll
  for (int j = 0; j < 4; ++j) *(bf16x8*)&cT[tb + j * 8] = o[j];
#pragma unroll
  for (int j = 0; j < 4; ++j)
#pragma unroll
    for (int e = 0; e < 8; ++e) o[j][e] = tq[j * 8 + e][d];
#pragma unroll
  for (int j = 0; j < 4; ++j) *(bf16x8*)&qT[tb + j * 8] = o[j];
}

// --------- S = cm @ qb^T + s0 + s1 + bias (fp16 out), 8 waves, BK=64 ----------
__global__ __launch_bounds__(512) void g_s(const bf16* __restrict__ Am,
                                           const bf16* __restrict__ Bm,
                                           const float* __restrict__ s0,
                                           const float* __restrict__ s1,
                                           const float* __restrict__ bias,
                                           f16* __restrict__ S) {
  __shared__ __align__(16) bf16 lds[2][2 * 128 * 64];   // A+B (each 128x64), 64 KB
  int f = blockIdx.x;
  int o = (f & 7) * 128 + (f >> 3);
  int bx = o & 7, by = (o >> 3) & 7, b = o >> 6;
  const bf16* Ab = Am + (size_t)b * Ln * Dn + (size_t)by * 128 * Dn;
  const bf16* Bb = Bm + (size_t)b * Ln * Dn + (size_t)bx * 128 * Dn;
  const int tid = threadIdx.x, wid = tid >> 6, lane = tid & 63;
  const int r = lane & 15, h = lane >> 4, wr = wid >> 2, wc = wid & 3;
  f32x4 acc[4][2];
  f32x4 zero = {0.f, 0.f, 0.f, 0.f};
#pragma unroll
  for (int i = 0; i < 4; ++i)
#pragma unroll
    for (int j = 0; j < 2; ++j) acc[i][j] = zero;

  stage512(Ab, Dn, 0, &lds[0][0], tid, wid);
  stage512(Bb, Dn, 0, &lds[0][8192], tid, wid);
  for (int t = 0; t < 4; ++t) {
    int cur = t & 1;
    if (t < 3) {
      stage512(Ab, Dn, (t + 1) * 64, &lds[cur ^ 1][0], tid, wid);
      stage512(Bb, Dn, (t + 1) * 64, &lds[cur ^ 1][8192], tid, wid);
      VMCNT(4);
    } else {
      VMCNT(0);
    }
    BARR;
    const bf16* lA = &lds[cur][0];
    const bf16* lB = &lds[cur][8192];
#pragma unroll
    for (int kk2 = 0; kk2 < 2; ++kk2) {
      int slot = (kk2 << 2) | h;
      bf16x8 av[4], bv[2];
#pragma unroll
      for (int i = 0; i < 4; ++i)
        av[i] = *(const bf16x8*)swzp(lA, (wr << 6) + (i << 4) + r, slot);
#pragma unroll
      for (int j = 0; j < 2; ++j)
        bv[j] = *(const bf16x8*)swzp(lB, (wc << 5) + (j << 4) + r, slot);
#pragma unroll
      for (int i = 0; i < 4; ++i)
#pragma unroll
        for (int j = 0; j < 2; ++j)
          acc[i][j] = __builtin_amdgcn_mfma_f32_16x16x32_bf16(av[i], bv[j], acc[i][j], 0, 0, 0);
    }
    LGKM0; BARR;
  }
  int grow = by * 128 + wr * 64, gcol = bx * 128 + wc * 32;
  float bvv = bias[0];
  size_t sb = (size_t)b * Ln * Ln;
#pragma unroll
  for (int j = 0; j < 2; ++j) {
    int n = gcol + j * 16 + r;
    float v1 = s1[b * Ln + n];
#pragma unroll
    for (int i = 0; i < 4; ++i) {
      int mb = grow + i * 16 + h * 4;
#pragma unroll
      for (int g = 0; g < 4; ++g) {
        float v0 = s0[b * Ln + mb + g];
        S[sb + (size_t)(mb + g) * Ln + n] = (f16)(acc[i][j][g] + v0 + v1 + bvv);
      }
    }
  }
}

// ---- merged softmax dispatch: blocks 0..1023 = batch-softmax+transpose (bp2,
// 18 KB two-pass tile), blocks 1024..5119 = row softmax. Both read only S. ----
__global__ __launch_bounds__(256) void k_sm(const f16* __restrict__ S,
                                            const float* __restrict__ qmask,
                                            const float* __restrict__ cmask,
                                            bf16* __restrict__ P1,
                                            bf16* __restrict__ P2) {
  __shared__ __align__(16) bf16 tile[8][32][36];   // 18 KB (bp2 blocks only)
  int blk = blockIdx.x;
  int t = threadIdx.x;
  if (blk < 1024) {
    // ---- batch-axis softmax (over b) + transpose: P2[b][j][i] ----
    int i0 = (blk >> 5) << 5, j0 = (blk & 31) << 5;
    int ti = t >> 3, tj4 = (t & 7) << 2;
    int i = i0 + ti;
    const f16* Sp = S + (size_t)i * Ln + j0 + tj4;
    float fm[16];
#pragma unroll
    for (int b = 0; b < 16; ++b) fm[b] = maskf(cmask[b * Ln + i]);
    f16x4 u[16];
#pragma unroll
    for (int b = 0; b < 16; ++b) u[b] = *(const f16x4*)(Sp + (size_t)b * Ln * Ln);
    float m[4] = {-3.4e38f, -3.4e38f, -3.4e38f, -3.4e38f};
#pragma unroll
    for (int b = 0; b < 16; ++b)
#pragma unroll
      for (int g = 0; g < 4; ++g) m[g] = fmaxf(m[g], (float)u[b][g] * fm[b]);
    float e[16][4];
    float s[4] = {0.f, 0.f, 0.f, 0.f};
#pragma unroll
    for (int b = 0; b < 16; ++b)
#pragma unroll
      for (int g = 0; g < 4; ++g) {
        e[b][g] = __expf((float)u[b][g] * fm[b] - m[g]);
        s[g] += e[b][g];
      }
#pragma unroll
    for (int g = 0; g < 4; ++g) s[g] = 1.0f / s[g];
    int jl = t >> 3, i4 = (t & 7) << 2;
#pragma unroll
    for (int half = 0; half < 2; ++half) {
      if (half) __syncthreads();   // protect tile reuse
#pragma unroll
      for (int bb = 0; bb < 8; ++bb) {
        int b = half * 8 + bb;
#pragma unroll
        for (int g = 0; g < 4; ++g) tile[bb][tj4 + g][ti] = (bf16)(e[b][g] * s[g]);
      }
      __syncthreads();
#pragma unroll
      for (int bb = 0; bb < 8; ++bb) {
        *(bf16x4*)&P2[((size_t)(half * 8 + bb) * Ln + j0 + jl) * Ln + i0 + i4] =
            *(const bf16x4*)&tile[bb][jl][i4];
      }
    }
  } else {
    // ---- row softmax: P1 = softmax_j(S * maskf(qmask_j)) ----
    int row = (blk - 1024) * 4 + (t >> 6);
    int b = row >> 10;
    int lane = t & 63;
    const f16* Sr = S + (size_t)row * Ln;
    const float* qm = qmask + (size_t)b * Ln;
    float v[16];
    float mx = -3.4e38f;
#pragma unroll
    for (int p = 0; p < 2; ++p) {
      f16x8 x = ((const f16x8*)Sr)[lane + (p << 6)];
      float4 m0 = ((const float4*)qm)[(lane + (p << 6)) * 2];
      float4 m1 = ((const float4*)qm)[(lane + (p << 6)) * 2 + 1];
      float mm[8] = {m0.x, m0.y, m0.z, m0.w, m1.x, m1.y, m1.z, m1.w};
#pragma unroll
      for (int e = 0; e < 8; ++e) {
        float xv = (float)x[e] * maskf(mm[e]);
        v[8 * p + e] = xv;
        mx = fmaxf(mx, xv);
      }
    }
#pragma unroll
    for (int off = 32; off; off >>= 1) mx = fmaxf(mx, __shfl_xor(mx, off));
    float sum = 0.f;
#pragma unroll
    for (int k = 0; k < 16; ++k) {
      v[k] = __expf(v[k] - mx);
      sum += v[k];
    }
#pragma unroll
    for (int off = 32; off; off >>= 1) sum += __shfl_xor(sum, off);
    float inv = 1.0f / sum;
    bf16* Pr = P1 + (size_t)row * Ln;
#pragma unroll
    for (int p = 0; p < 2; ++p) {
      bf16x8 o;
#pragma unroll
      for (int e = 0; e < 8; ++e) o[e] = (bf16)(v[8 * p + e] * inv);
      ((bf16x8*)Pr)[lane + (p << 6)] = o;
    }
  }
}

// ------- TT[b][d][jq] = cT @ P2^T  (128x128 tiles, 8 waves, BK=64, vmcnt) ------
__global__ __launch_bounds__(512) void g_t(const bf16* __restrict__ cT,
                                           const bf16* __restrict__ P2,
                                           bf16* __restrict__ TT) {
  __shared__ __align__(16) bf16 lds[2][2 * 128 * 64];   // A+B (each 128x64), 64 KB
  int f = blockIdx.x;
  int o = (f & 7) * 32 + (f >> 3);   // 256 blocks, XCD-chunked
  int b = o >> 4, md = (o >> 3) & 1, nb = o & 7;
  const bf16* Ab = cT + (size_t)b * Dn * Ln + (size_t)md * 128 * Ln;
  const bf16* Bb = P2 + (size_t)b * Ln * Ln + (size_t)nb * 128 * Ln;
  const int tid = threadIdx.x, wid = tid >> 6, lane = tid & 63;
  const int r = lane & 15, h = lane >> 4, wr = wid >> 2, wc = wid & 3;
  f32x4 acc[4][2];
  f32x4 zero = {0.f, 0.f, 0.f, 0.f};
#pragma unroll
  for (int i = 0; i < 4; ++i)
#pragma unroll
    for (int j = 0; j < 2; ++j) acc[i][j] = zero;

  stage512(Ab, Ln, 0, &lds[0][0], tid, wid);
  stage512(Bb, Ln, 0, &lds[0][8192], tid, wid);
  for (int t = 0; t < 16; ++t) {
    int cur = t & 1;
    if (t < 15) {
      stage512(Ab, Ln, (t + 1) * 64, &lds[cur ^ 1][0], tid, wid);
      stage512(Bb, Ln, (t + 1) * 64, &lds[cur ^ 1][8192], tid, wid);
      VMCNT(4);
    } else {
      VMCNT(0);
    }
    BARR;
    const bf16* lA = &lds[cur][0];
    const bf16* lB = &lds[cur][8192];
#pragma unroll
    for (int kk2 = 0; kk2 < 2; ++kk2) {
      int slot = (kk2 << 2) | h;
      bf16x8 av[4], bv[2];
#pragma unroll
      for (int i = 0; i < 4; ++i)
        av[i] = *(const bf16x8*)swzp(lA, (wr << 6) + (i << 4) + r, slot);
#pragma unroll
      for (int j = 0; j < 2; ++j)
        bv[j] = *(const bf16x8*)swzp(lB, (wc << 5) + (j << 4) + r, slot);
#pragma unroll
      for (int i = 0; i < 4; ++i)
#pragma unroll
        for (int j = 0; j < 2; ++j)
          acc[i][j] = __builtin_amdgcn_mfma_f32_16x16x32_bf16(av[i], bv[j], acc[i][j], 0, 0, 0);
    }
    LGKM0; BARR;
  }
  size_t ob = (size_t)b * Dn * Ln;
  int dbase = md * 128 + wr * 64, cbase = nb * 128 + wc * 32;
#pragma unroll
  for (int i = 0; i < 4; ++i)
#pragma unroll
    for (int j = 0; j < 2; ++j) {
      int n = cbase + j * 16 + r;
#pragma unroll
      for (int g = 0; g < 4; ++g)
        TT[ob + (size_t)(dbase + i * 16 + h * 4 + g) * Ln + n] = (bf16)acc[i][j][g];
    }
}

// ------- split: 512 blocks, 2 blocks/CU. half=0: C2Q = P1 @ qT^T -> o0,o1,o2;
// half=1: Q2C = P1 @ TT^T -> o3. g_t-shaped per-wave geometry (A+B, 64 KB LDS,
// VMCNT(4)); co-resident blocks phase-offset -> vmcnt/barrier stalls overlap. --
__global__ __launch_bounds__(512) void g_cq(const bf16* __restrict__ P1,
                                            const bf16* __restrict__ qT,
                                            const bf16* __restrict__ TT,
                                            const float* __restrict__ c,
                                            float* __restrict__ out) {
  __shared__ __align__(16) bf16 lds[2][2 * 128 * 64];   // A+B (each 128x64), 64 KB
  int f = blockIdx.x;              // 512 blocks
  int half = (f >> 8) & 1;         // 0: qT (acc -> o0,o1,o2); 1: TT (acc -> o3)
  int g8 = f & 255;
  int o = (g8 & 7) * 32 + (g8 >> 3);   // XCD-chunked within each half
  int b = o >> 4, by = (o >> 1) & 7, bx = o & 1;
  const bf16* Ab = P1 + (size_t)b * Ln * Ln + (size_t)by * 128 * Ln;
  const bf16* Bb = (half ? TT : qT) + (size_t)b * Dn * Ln + (size_t)bx * 128 * Ln;
  const int tid = threadIdx.x, wid = tid >> 6, lane = tid & 63;
  const int r = lane & 15, h = lane >> 4, wr = wid >> 2, wc = wid & 3;
  f32x4 acc[4][2];
  f32x4 zero = {0.f, 0.f, 0.f, 0.f};
#pragma unroll
  for (int i = 0; i < 4; ++i)
#pragma unroll
    for (int j = 0; j < 2; ++j) acc[i][j] = zero;

  stage512(Ab, Ln, 0, &lds[0][0], tid, wid);
  stage512(Bb, Ln, 0, &lds[0][8192], tid, wid);
  for (int t = 0; t < 16; ++t) {
    int cur = t & 1;
    if (t < 15) {
      stage512(Ab, Ln, (t + 1) * 64, &lds[cur ^ 1][0], tid, wid);
      stage512(Bb, Ln, (t + 1) * 64, &lds[cur ^ 1][8192], tid, wid);
      VMCNT(4);
    } else {
      VMCNT(0);
    }
    BARR;
    const bf16* lA = &lds[cur][0];
    const bf16* lB = &lds[cur][8192];
#pragma unroll
    for (int kk2 = 0; kk2 < 2; ++kk2) {
      int slot = (kk2 << 2) | h;
      bf16x8 av[4], bv[2];
#pragma unroll
      for (int i = 0; i < 4; ++i)
        av[i] = *(const bf16x8*)swzp(lA, (wr << 6) + (i << 4) + r, slot);
#pragma unroll
      for (int j = 0; j < 2; ++j)
        bv[j] = *(const bf16x8*)swzp(lB, (wc << 5) + (j << 4) + r, slot);
#pragma unroll
      for (int i = 0; i < 4; ++i)
#pragma unroll
        for (int j = 0; j < 2; ++j)
          acc[i][j] = __builtin_amdgcn_mfma_f32_16x16x32_bf16(av[i], bv[j], acc[i][j], 0, 0, 0);
    }
    LGKM0; BARR;
  }

  int grow = by * 128 + wr * 64, gcol = bx * 128 + wc * 32;
  const float* cb = c + (size_t)b * Ln * Dn;
  float* o0 = out + (size_t)(0 * Bn + b) * Ln * Dn;
  float* o1 = out + (size_t)(1 * Bn + b) * Ln * Dn;
  float* o2 = out + (size_t)(2 * Bn + b) * Ln * Dn;
  float* o3 = out + (size_t)(3 * Bn + b) * Ln * Dn;
#pragma unroll
  for (int j = 0; j < 2; ++j) {
    int n = gcol + j * 16 + r;
#pragma unroll
    for (int i = 0; i < 4; ++i) {
      int mb = grow + i * 16 + h * 4;
#pragma unroll
      for (int g = 0; g < 4; ++g) {
        float v = acc[i][j][g];
        size_t off = (size_t)(mb + g) * Dn + n;
        float cc = cb[off];
        if (half == 0) {
          o0[off] = cc;
          o1[off] = v;
          o2[off] = cc * v;
        } else {
          o3[off] = cc * v;
        }
      }
    }
  }
}

extern "C" void kernel_launch(void* const* d_in, const int* in_sizes, int n_in,
                              void* d_out, int out_size, void* d_ws, size_t ws_size,
                              hipStream_t stream) {
  const float* c = (const float*)d_in[0];
  const float* q = (const float*)d_in[1];
  const float* cmask = (const float*)d_in[2];
  const float* qmask = (const float*)d_in[3];
  const float* cw = (const float*)d_in[4];
  const float* qw = (const float*)d_in[5];
  const float* cqw = (const float*)d_in[6];
  const float* bias = (const float*)d_in[7];
  float* out = (float*)d_out;

  char* w = (char*)d_ws;
  f16* S = (f16*)w;       w += (size_t)Bn * Ln * Ln * 2;
  bf16* P1 = (bf16*)w;    w += (size_t)Bn * Ln * Ln * 2;
  bf16* P2 = (bf16*)w;    w += (size_t)Bn * Ln * Ln * 2;
  bf16* cm = (bf16*)w;    w += (size_t)Bn * Ln * Dn * 2;
  bf16* qb = (bf16*)w;    w += (size_t)Bn * Ln * Dn * 2;
  bf16* cT = (bf16*)w;    w += (size_t)Bn * Dn * Ln * 2;
  bf16* qT = (bf16*)w;    w += (size_t)Bn * Dn * Ln * 2;
  bf16* TT = (bf16*)w;    w += (size_t)Bn * Dn * Ln * 2;
  float* s0 = (float*)w;  w += (size_t)Bn * Ln * 4;
  float* s1 = (float*)w;  w += (size_t)Bn * Ln * 4;
  if ((size_t)(w - (char*)d_ws) > ws_size) return;  // ws too small: fail visibly

  k_prep2<<<dim3(Bn * Ln / 32), 256, 0, stream>>>(c, q, cw, qw, cqw, cm, qb, cT, qT, s0, s1);
  g_s<<<dim3(1024), 512, 0, stream>>>(cm, qb, s0, s1, bias, S);
  k_sm<<<dim3(1024 + Bn * Ln / 4), 256, 0, stream>>>(S, qmask, cmask, P1, P2);
  g_t<<<dim3(256), 512, 0, stream>>>(cT, P2, TT);
  g_cq<<<dim3(512), 512, 0, stream>>>(P1, qT, TT, c, out);
}